// Round 1
// baseline (314.813 us; speedup 1.0000x reference)
//
#include <hip/hip_runtime.h>

typedef __bf16 bf16_t;
typedef __bf16 bf16x8 __attribute__((ext_vector_type(8)));
typedef __bf16 bf16x4 __attribute__((ext_vector_type(4)));
typedef float  f32x4  __attribute__((ext_vector_type(4)));

#define DEVFN __device__ __forceinline__

DEVFN void gl_lds16(void* lds_base, const void* gsrc) {
  __builtin_amdgcn_global_load_lds(
      (const __attribute__((address_space(1))) void*)gsrc,
      (__attribute__((address_space(3))) void*)lds_base, 16, 0, 0);
}

// swizzled byte offset within a [rows][128B] LDS tile: chunk c of row r lives at c^(r&7)
#define SWZ128(row, bo) (((row) << 7) + ((((bo) >> 4) ^ ((row) & 7)) << 4) + ((bo) & 15))

// ---------------------------------------------------------------- converts
__global__ __launch_bounds__(256) void k_f32_to_bf16(
    const float* __restrict__ x, bf16_t* __restrict__ y, int n4) {
  int i = blockIdx.x * 256 + threadIdx.x;
  int stride = gridDim.x * 256;
  for (; i < n4; i += stride) {
    float4 v = reinterpret_cast<const float4*>(x)[i];
    bf16x4 o;
    o[0] = (bf16_t)v.x; o[1] = (bf16_t)v.y; o[2] = (bf16_t)v.z; o[3] = (bf16_t)v.w;
    reinterpret_cast<bf16x4*>(y)[i] = o;
  }
}

// w [K,N] f32 -> wt [N,K] bf16
__global__ __launch_bounds__(256) void k_transpose_w(
    const float* __restrict__ w, bf16_t* __restrict__ wt, int K, int N) {
  __shared__ float t[64][65];
  const int tn = N >> 6;
  const int bk = (blockIdx.x / tn) << 6;
  const int bn = (blockIdx.x % tn) << 6;
  const int rr = threadIdx.x >> 4;
  const int cc = (threadIdx.x & 15) << 2;
#pragma unroll
  for (int i = 0; i < 4; ++i) {
    int r = i * 16 + rr;
    float4 v = *reinterpret_cast<const float4*>(&w[(size_t)(bk + r) * N + bn + cc]);
    t[r][cc] = v.x; t[r][cc + 1] = v.y; t[r][cc + 2] = v.z; t[r][cc + 3] = v.w;
  }
  __syncthreads();
#pragma unroll
  for (int i = 0; i < 4; ++i) {
    int n = i * 16 + rr;
    bf16x4 o;
    o[0] = (bf16_t)t[cc][n];     o[1] = (bf16_t)t[cc + 1][n];
    o[2] = (bf16_t)t[cc + 2][n]; o[3] = (bf16_t)t[cc + 3][n];
    *reinterpret_cast<bf16x4*>(&wt[(size_t)(bn + n) * K + bk + cc]) = o;
  }
}

// Vp [B*LK, 1024] bf16 -> Vt [(b*16+h)*64 + d][LK] bf16
__global__ __launch_bounds__(256) void k_transpose_v(
    const bf16_t* __restrict__ Vp, bf16_t* __restrict__ Vt) {
  const int kt = blockIdx.x & 15;
  const int bh = blockIdx.x >> 4;
  const int b = bh >> 4, h = bh & 15;
  __shared__ unsigned short t[64][72];
#pragma unroll
  for (int i = 0; i < 2; ++i) {
    int cid = i * 256 + threadIdx.x;
    int r = cid >> 3, c = (cid & 7) * 8;
    uint4 v = *reinterpret_cast<const uint4*>(
        Vp + ((size_t)(b * 1024 + kt * 64 + r)) * 1024 + h * 64 + c);
    const unsigned short* pv = reinterpret_cast<const unsigned short*>(&v);
#pragma unroll
    for (int j = 0; j < 8; ++j) t[r][c + j] = pv[j];
  }
  __syncthreads();
#pragma unroll
  for (int i = 0; i < 2; ++i) {
    int cid = i * 256 + threadIdx.x;
    int d = cid >> 3, c = (cid & 7) * 8;
    unsigned short tmp[8];
#pragma unroll
    for (int j = 0; j < 8; ++j) tmp[j] = t[c + j][d];
    *reinterpret_cast<uint4*>(Vt + ((size_t)(bh * 64 + d)) * 1024 + kt * 64 + c) =
        *reinterpret_cast<uint4*>(tmp);
  }
}

__global__ __launch_bounds__(256) void k_vsum(
    const bf16_t* __restrict__ Vt, float* __restrict__ Vs) {
  int row = blockIdx.x * 4 + (threadIdx.x >> 6);
  int lane = threadIdx.x & 63;
  float s = 0.f;
#pragma unroll
  for (int i = 0; i < 16; ++i) s += (float)Vt[(size_t)row * 1024 + i * 64 + lane];
#pragma unroll
  for (int off = 32; off > 0; off >>= 1) s += __shfl_xor(s, off, 64);
  if (lane == 0) Vs[row] = s;
}

// ---------------------------------------------------------------- GEMM: C[M,N] = A[M,K] * Bt[N,K]^T, bf16 out
__global__ __launch_bounds__(256) void k_gemm_bt(
    const bf16_t* __restrict__ A, const bf16_t* __restrict__ Bt,
    bf16_t* __restrict__ C, int M, int N, int K) {
  (void)M;
  __shared__ bf16_t As[128 * 32];
  __shared__ bf16_t Bs[128 * 32];
  const int tn = N >> 7;
  const int m0 = (blockIdx.x / tn) << 7;
  const int n0 = (blockIdx.x % tn) << 7;
  const int lane = threadIdx.x & 63;
  const int wv = threadIdx.x >> 6;
  const int wr = (wv >> 1) * 64, wc = (wv & 1) * 64;
  const int lr = lane & 15, lk = lane >> 4;
  const int so0 = wv * 2048 + lane * 16;
  const int so1 = so0 + 1024;
  const int r0 = so0 >> 6, c0 = so0 & 63;
  const int r1 = so1 >> 6, c1 = so1 & 63;
  char* AsB = (char*)As;
  char* BsB = (char*)Bs;
  const char* Apc = (const char*)A;
  const char* Btc = (const char*)Bt;
  f32x4 zro = {0.f, 0.f, 0.f, 0.f};
  f32x4 acc[4][4];
#pragma unroll
  for (int i = 0; i < 4; ++i)
#pragma unroll
    for (int j = 0; j < 4; ++j) acc[i][j] = zro;

  for (int kt = 0; kt < K; kt += 32) {
    gl_lds16(AsB + wv * 2048,        Apc + ((size_t)(m0 + r0) * K + kt) * 2 + c0);
    gl_lds16(AsB + wv * 2048 + 1024, Apc + ((size_t)(m0 + r1) * K + kt) * 2 + c1);
    gl_lds16(BsB + wv * 2048,        Btc + ((size_t)(n0 + r0) * K + kt) * 2 + c0);
    gl_lds16(BsB + wv * 2048 + 1024, Btc + ((size_t)(n0 + r1) * K + kt) * 2 + c1);
    __syncthreads();
    bf16x8 af[4], bfr[4];
#pragma unroll
    for (int i = 0; i < 4; ++i)
      af[i] = *(const bf16x8*)(AsB + (wr + i * 16 + lr) * 64 + lk * 16);
#pragma unroll
    for (int j = 0; j < 4; ++j)
      bfr[j] = *(const bf16x8*)(BsB + (wc + j * 16 + lr) * 64 + lk * 16);
#pragma unroll
    for (int i = 0; i < 4; ++i)
#pragma unroll
      for (int j = 0; j < 4; ++j)
        acc[i][j] = __builtin_amdgcn_mfma_f32_16x16x32_bf16(af[i], bfr[j], acc[i][j], 0, 0, 0);
    __syncthreads();
  }
#pragma unroll
  for (int i = 0; i < 4; ++i)
#pragma unroll
    for (int j = 0; j < 4; ++j)
#pragma unroll
      for (int r = 0; r < 4; ++r)
        C[(size_t)(m0 + wr + i * 16 + lk * 4 + r) * N + n0 + wc + j * 16 + lr] =
            (bf16_t)acc[i][j][r];
}

// Y[M,N] f32 = A1*B1t^T + A2*B2t^T + bias
__global__ __launch_bounds__(256) void k_gemm_final(
    const bf16_t* __restrict__ A1, const bf16_t* __restrict__ B1t, int K1,
    const bf16_t* __restrict__ A2, const bf16_t* __restrict__ B2t, int K2,
    const float* __restrict__ bias, float* __restrict__ Y, int N) {
  __shared__ bf16_t As[128 * 32];
  __shared__ bf16_t Bs[128 * 32];
  const int tn = N >> 7;
  const int m0 = (blockIdx.x / tn) << 7;
  const int n0 = (blockIdx.x % tn) << 7;
  const int lane = threadIdx.x & 63;
  const int wv = threadIdx.x >> 6;
  const int wr = (wv >> 1) * 64, wc = (wv & 1) * 64;
  const int lr = lane & 15, lk = lane >> 4;
  const int so0 = wv * 2048 + lane * 16;
  const int so1 = so0 + 1024;
  const int r0 = so0 >> 6, c0 = so0 & 63;
  const int r1 = so1 >> 6, c1 = so1 & 63;
  char* AsB = (char*)As;
  char* BsB = (char*)Bs;
  f32x4 zro = {0.f, 0.f, 0.f, 0.f};
  f32x4 acc[4][4];
#pragma unroll
  for (int i = 0; i < 4; ++i)
#pragma unroll
    for (int j = 0; j < 4; ++j) acc[i][j] = zro;

  const bf16_t* Ap[2] = {A1, A2};
  const bf16_t* Bp[2] = {B1t, B2t};
  const int Kp_[2] = {K1, K2};
  for (int ph = 0; ph < 2; ++ph) {
    const char* Apc = (const char*)Ap[ph];
    const char* Btc = (const char*)Bp[ph];
    const int K = Kp_[ph];
    for (int kt = 0; kt < K; kt += 32) {
      gl_lds16(AsB + wv * 2048,        Apc + ((size_t)(m0 + r0) * K + kt) * 2 + c0);
      gl_lds16(AsB + wv * 2048 + 1024, Apc + ((size_t)(m0 + r1) * K + kt) * 2 + c1);
      gl_lds16(BsB + wv * 2048,        Btc + ((size_t)(n0 + r0) * K + kt) * 2 + c0);
      gl_lds16(BsB + wv * 2048 + 1024, Btc + ((size_t)(n0 + r1) * K + kt) * 2 + c1);
      __syncthreads();
      bf16x8 af[4], bfr[4];
#pragma unroll
      for (int i = 0; i < 4; ++i)
        af[i] = *(const bf16x8*)(AsB + (wr + i * 16 + lr) * 64 + lk * 16);
#pragma unroll
      for (int j = 0; j < 4; ++j)
        bfr[j] = *(const bf16x8*)(BsB + (wc + j * 16 + lr) * 64 + lk * 16);
#pragma unroll
      for (int i = 0; i < 4; ++i)
#pragma unroll
        for (int j = 0; j < 4; ++j)
          acc[i][j] = __builtin_amdgcn_mfma_f32_16x16x32_bf16(af[i], bfr[j], acc[i][j], 0, 0, 0);
      __syncthreads();
    }
  }
#pragma unroll
  for (int i = 0; i < 4; ++i)
#pragma unroll
    for (int j = 0; j < 4; ++j) {
      float bv = bias[n0 + wc + j * 16 + lr];
#pragma unroll
      for (int r = 0; r < 4; ++r)
        Y[(size_t)(m0 + wr + i * 16 + lk * 4 + r) * N + n0 + wc + j * 16 + lr] =
            acc[i][j][r] + bv;
    }
}

// ---------------------------------------------------------------- attention
// out_heads = (Vsum - softmax(QK^T/8) V) / 1023, bf16, layout [B*LQ, H*64]
__global__ __launch_bounds__(256) void k_attn(
    const bf16_t* __restrict__ Qp, const bf16_t* __restrict__ Kp,
    const bf16_t* __restrict__ Vt, const float* __restrict__ Vsum,
    bf16_t* __restrict__ Aout) {
  const int qt = blockIdx.x & 15;
  const int bh = blockIdx.x >> 4;
  const int b = bh >> 4, h = bh & 15;
  __shared__ bf16_t Qs[64 * 64], Ks[64 * 64], Vs[64 * 64];
  __shared__ bf16_t Ps[4][16 * 64];
  const int lane = threadIdx.x & 63;
  const int wv = threadIdx.x >> 6;
  const int lr = lane & 15, lk = lane >> 4;
  char* QsB = (char*)Qs;
  char* KsB = (char*)Ks;
  char* VsB = (char*)Vs;
  char* PsB = (char*)(&Ps[wv][0]);

  const int o0 = wv * 2048 + lane * 16;
  const int o1 = o0 + 1024;
  const int row0 = o0 >> 7, row1 = o1 >> 7;
  const int sc0 = ((((o0 >> 4) & 7) ^ (row0 & 7)) << 4);
  const int sc1 = ((((o1 >> 4) & 7) ^ (row1 & 7)) << 4);

  // stage Q (rows = q local, 128B rows, swizzled source)
  gl_lds16(QsB + wv * 2048,
           (const char*)(Qp + ((size_t)(b * 1024 + qt * 64 + row0)) * 1024 + h * 64) + sc0);
  gl_lds16(QsB + wv * 2048 + 1024,
           (const char*)(Qp + ((size_t)(b * 1024 + qt * 64 + row1)) * 1024 + h * 64) + sc1);
  __syncthreads();

  bf16x8 qa[2];
#pragma unroll
  for (int ks = 0; ks < 2; ++ks)
    qa[ks] = *(const bf16x8*)(QsB + SWZ128(wv * 16 + lr, ks * 64 + lk * 16));

  f32x4 zro = {0.f, 0.f, 0.f, 0.f};
  f32x4 oacc[4];
#pragma unroll
  for (int g = 0; g < 4; ++g) oacc[g] = zro;
  float mrow[4] = {-1e30f, -1e30f, -1e30f, -1e30f};
  float lrow[4] = {0.f, 0.f, 0.f, 0.f};

  for (int kt = 0; kt < 16; ++kt) {
    gl_lds16(KsB + wv * 2048,
             (const char*)(Kp + ((size_t)(b * 1024 + kt * 64 + row0)) * 1024 + h * 64) + sc0);
    gl_lds16(KsB + wv * 2048 + 1024,
             (const char*)(Kp + ((size_t)(b * 1024 + kt * 64 + row1)) * 1024 + h * 64) + sc1);
    gl_lds16(VsB + wv * 2048,
             (const char*)(Vt + ((size_t)(bh * 64 + row0)) * 1024 + kt * 64) + sc0);
    gl_lds16(VsB + wv * 2048 + 1024,
             (const char*)(Vt + ((size_t)(bh * 64 + row1)) * 1024 + kt * 64) + sc1);
    __syncthreads();

    // S = Q K^T  (rows q, cols kk)
    f32x4 sacc[4];
#pragma unroll
    for (int g = 0; g < 4; ++g) sacc[g] = zro;
#pragma unroll
    for (int ks = 0; ks < 2; ++ks)
#pragma unroll
      for (int g = 0; g < 4; ++g) {
        bf16x8 kb = *(const bf16x8*)(KsB + SWZ128(g * 16 + lr, ks * 64 + lk * 16));
        sacc[g] = __builtin_amdgcn_mfma_f32_16x16x32_bf16(qa[ks], kb, sacc[g], 0, 0, 0);
      }

    // online softmax (scores = sacc/8)
    float tmax[4];
#pragma unroll
    for (int r = 0; r < 4; ++r) {
      float m = fmaxf(fmaxf(sacc[0][r], sacc[1][r]), fmaxf(sacc[2][r], sacc[3][r])) * 0.125f;
      m = fmaxf(m, __shfl_xor(m, 1, 64));
      m = fmaxf(m, __shfl_xor(m, 2, 64));
      m = fmaxf(m, __shfl_xor(m, 4, 64));
      m = fmaxf(m, __shfl_xor(m, 8, 64));
      tmax[r] = m;
    }
    float corr[4], ps[4];
#pragma unroll
    for (int r = 0; r < 4; ++r) {
      float mn = fmaxf(mrow[r], tmax[r]);
      corr[r] = __expf(mrow[r] - mn);
      mrow[r] = mn;
      ps[r] = 0.f;
    }
#pragma unroll
    for (int g = 0; g < 4; ++g)
#pragma unroll
      for (int r = 0; r < 4; ++r) {
        float p = __expf(sacc[g][r] * 0.125f - mrow[r]);
        ps[r] += p;
        int qloc = lk * 4 + r;
        int bo = (g * 16 + lr) * 2;
        *(bf16_t*)(PsB + SWZ128(qloc, bo)) = (bf16_t)p;
      }
#pragma unroll
    for (int r = 0; r < 4; ++r) {
      float s = ps[r];
      s += __shfl_xor(s, 1, 64);
      s += __shfl_xor(s, 2, 64);
      s += __shfl_xor(s, 4, 64);
      s += __shfl_xor(s, 8, 64);
      lrow[r] = lrow[r] * corr[r] + s;
    }
#pragma unroll
    for (int g = 0; g < 4; ++g)
#pragma unroll
      for (int r = 0; r < 4; ++r) oacc[g][r] *= corr[r];

    // O += P V  (A = P rows q, B = Vt cols d)
#pragma unroll
    for (int ks = 0; ks < 2; ++ks) {
      bf16x8 pa = *(const bf16x8*)(PsB + SWZ128(lr, ks * 64 + lk * 16));
#pragma unroll
      for (int gd = 0; gd < 4; ++gd) {
        bf16x8 vb = *(const bf16x8*)(VsB + SWZ128(gd * 16 + lr, ks * 64 + lk * 16));
        oacc[gd] = __builtin_amdgcn_mfma_f32_16x16x32_bf16(pa, vb, oacc[gd], 0, 0, 0);
      }
    }
    __syncthreads();
  }

#pragma unroll
  for (int gd = 0; gd < 4; ++gd)
#pragma unroll
    for (int r = 0; r < 4; ++r) {
      int d = gd * 16 + lr;
      int qrow = qt * 64 + wv * 16 + lk * 4 + r;
      float attnv = oacc[gd][r] / lrow[r];
      float val = (Vsum[bh * 64 + d] - attnv) * (1.0f / 1023.0f);
      Aout[((size_t)(b * 1024 + qrow)) * 1024 + h * 64 + d] = (bf16_t)val;
    }
}

// ---------------------------------------------------------------- layernorm
__global__ __launch_bounds__(256) void k_ln(
    const float* __restrict__ Y, const float* __restrict__ gamma,
    const float* __restrict__ beta, float* __restrict__ out) {
  const int row = blockIdx.x, tid = threadIdx.x;
  const float4 x = reinterpret_cast<const float4*>(Y + (size_t)row * 1024)[tid];
  float s = x.x + x.y + x.z + x.w;
  float q = x.x * x.x + x.y * x.y + x.z * x.z + x.w * x.w;
#pragma unroll
  for (int off = 32; off > 0; off >>= 1) {
    s += __shfl_xor(s, off, 64);
    q += __shfl_xor(q, off, 64);
  }
  __shared__ float ss[4], qs[4];
  if ((tid & 63) == 0) { ss[tid >> 6] = s; qs[tid >> 6] = q; }
  __syncthreads();
  s = ss[0] + ss[1] + ss[2] + ss[3];
  q = qs[0] + qs[1] + qs[2] + qs[3];
  float mean = s * (1.f / 1024.f);
  float var = q * (1.f / 1024.f) - mean * mean;
  float rstd = rsqrtf(var + 1e-5f);
  float4 g = reinterpret_cast<const float4*>(gamma)[tid];
  float4 bt = reinterpret_cast<const float4*>(beta)[tid];
  float4 o;
  o.x = (x.x - mean) * rstd * g.x + bt.x;
  o.y = (x.y - mean) * rstd * g.y + bt.y;
  o.z = (x.z - mean) * rstd * g.z + bt.z;
  o.w = (x.w - mean) * rstd * g.w + bt.w;
  reinterpret_cast<float4*>(out + (size_t)row * 1024)[tid] = o;
}

// ---------------------------------------------------------------- launch
extern "C" void kernel_launch(void* const* d_in, const int* in_sizes, int n_in,
                              void* d_out, int out_size, void* d_ws, size_t ws_size,
                              hipStream_t stream) {
  (void)in_sizes; (void)n_in; (void)out_size;
  const float* q       = (const float*)d_in[0];
  const float* k       = (const float*)d_in[1];
  const float* v       = (const float*)d_in[2];
  const float* w_qs    = (const float*)d_in[3];
  const float* w_ks    = (const float*)d_in[4];
  const float* w_vs    = (const float*)d_in[5];
  const float* fc_w    = (const float*)d_in[6];
  const float* resid_w = (const float*)d_in[7];
  const float* resid_b = (const float*)d_in[8];
  const float* ln_g    = (const float*)d_in[9];
  const float* ln_b    = (const float*)d_in[10];
  float* out = (float*)d_out;
  char* ws = (char*)d_ws;

  if (ws_size < (size_t)122716160) return;  // need ~117 MB

  bf16_t* qb   = (bf16_t*)(ws + 0);
  bf16_t* kb   = (bf16_t*)(ws + 12582912);
  bf16_t* vb   = (bf16_t*)(ws + 29360128);
  float*  Y    = (float*)(ws + 12582912);   // aliases kb+vb (dead after projections)
  bf16_t* wqsT = (bf16_t*)(ws + 46137344);
  bf16_t* wksT = (bf16_t*)(ws + 47710208);
  bf16_t* wvsT = (bf16_t*)(ws + 49807360);
  bf16_t* fcwT = (bf16_t*)(ws + 51904512);
  bf16_t* rswT = (bf16_t*)(ws + 54001664);
  bf16_t* Qp   = (bf16_t*)(ws + 55574528);
  bf16_t* Kp   = (bf16_t*)(ws + 72351744);
  bf16_t* Vp   = (bf16_t*)(ws + 89128960);
  bf16_t* Aout = (bf16_t*)(ws + 89128960);  // aliases Vp (dead after transpose_v)
  bf16_t* VtT  = (bf16_t*)(ws + 105906176);
  float*  Vsm  = (float*)(ws + 122683392);

  k_f32_to_bf16<<<4096, 256, 0, stream>>>(q, qb, 1572864);
  k_f32_to_bf16<<<4096, 256, 0, stream>>>(k, kb, 2097152);
  k_f32_to_bf16<<<4096, 256, 0, stream>>>(v, vb, 2097152);
  k_transpose_w<<<192, 256, 0, stream>>>(w_qs, wqsT, 768, 1024);
  k_transpose_w<<<256, 256, 0, stream>>>(w_ks, wksT, 1024, 1024);
  k_transpose_w<<<256, 256, 0, stream>>>(w_vs, wvsT, 1024, 1024);
  k_transpose_w<<<256, 256, 0, stream>>>(fc_w, fcwT, 1024, 1024);
  k_transpose_w<<<192, 256, 0, stream>>>(resid_w, rswT, 768, 1024);
  k_gemm_bt<<<512, 256, 0, stream>>>(qb, wqsT, Qp, 8192, 1024, 768);
  k_gemm_bt<<<512, 256, 0, stream>>>(kb, wksT, Kp, 8192, 1024, 1024);
  k_gemm_bt<<<512, 256, 0, stream>>>(vb, wvsT, Vp, 8192, 1024, 1024);
  k_transpose_v<<<2048, 256, 0, stream>>>(Vp, VtT);
  k_vsum<<<2048, 256, 0, stream>>>(VtT, Vsm);
  k_attn<<<2048, 256, 0, stream>>>(Qp, Kp, VtT, Vsm, Aout);
  k_gemm_final<<<512, 256, 0, stream>>>(Aout, fcwT, 1024, qb, rswT, 768, resid_b, Y, 1024);
  k_ln<<<8192, 256, 0, stream>>>(Y, ln_g, ln_b, out);
}

// Round 3
// 246.020 us; speedup vs baseline: 1.2796x; 1.2796x over previous
//
#include <hip/hip_runtime.h>

typedef __bf16 bf16_t;
typedef __bf16 bf16x8 __attribute__((ext_vector_type(8)));
typedef __bf16 bf16x4 __attribute__((ext_vector_type(4)));
typedef float  f32x4  __attribute__((ext_vector_type(4)));

#define DEVFN __device__ __forceinline__

DEVFN void gl_lds16(void* lds_base, const void* gsrc) {
  __builtin_amdgcn_global_load_lds(
      (const __attribute__((address_space(1))) void*)gsrc,
      (__attribute__((address_space(3))) void*)lds_base, 16, 0, 0);
}

// swizzled byte offset within a [rows][128B] LDS tile: chunk c of row r lives at c^(r&7)
#define SWZ128(row, bo) (((row) << 7) + ((((bo) >> 4) ^ ((row) & 7)) << 4) + ((bo) & 15))

// ---------------------------------------------------------------- fused converts (+ Vsum zero)
__global__ __launch_bounds__(256) void k_convert_all(
    const float* __restrict__ q, const float* __restrict__ k, const float* __restrict__ v,
    bf16_t* __restrict__ qb, bf16_t* __restrict__ kb, bf16_t* __restrict__ vb,
    float* __restrict__ Vs) {
  if (blockIdx.x == 0) {
    // zero ALL of Vsum (8*16*64 = 8192 floats) — atomicAdd target, must be
    // re-zeroed every call or values accumulate across graph replays.
    for (int j = threadIdx.x; j < 8192; j += 256) Vs[j] = 0.f;
  }
  const int NQ = 1572864, NK = 2097152, NT = NQ + 2 * NK;
  int stride = gridDim.x * 256;
  for (int i = blockIdx.x * 256 + threadIdx.x; i < NT; i += stride) {
    const float* src; bf16_t* dst; int off;
    if (i < NQ)           { src = q; dst = qb; off = i; }
    else if (i < NQ + NK) { src = k; dst = kb; off = i - NQ; }
    else                  { src = v; dst = vb; off = i - NQ - NK; }
    float4 vv = reinterpret_cast<const float4*>(src)[off];
    bf16x4 o;
    o[0] = (bf16_t)vv.x; o[1] = (bf16_t)vv.y; o[2] = (bf16_t)vv.z; o[3] = (bf16_t)vv.w;
    reinterpret_cast<bf16x4*>(dst)[off] = o;
  }
}

// ---------------------------------------------------------------- fused weight transposes
// w [K,1024] f32 -> wt [1024,K] bf16, five matrices in one launch
__global__ __launch_bounds__(256) void k_transpose_all(
    const float* __restrict__ w_qs, const float* __restrict__ w_ks,
    const float* __restrict__ w_vs, const float* __restrict__ fc_w,
    const float* __restrict__ resid_w,
    bf16_t* __restrict__ wqsT, bf16_t* __restrict__ wksT, bf16_t* __restrict__ wvsT,
    bf16_t* __restrict__ fcwT, bf16_t* __restrict__ rswT) {
  int bid = blockIdx.x;
  const float* w; bf16_t* wt; int K;
  if (bid < 192)      { w = w_qs;    wt = wqsT; K = 768; }
  else if (bid < 448) { w = w_ks;    wt = wksT; K = 1024; bid -= 192; }
  else if (bid < 704) { w = w_vs;    wt = wvsT; K = 1024; bid -= 448; }
  else if (bid < 960) { w = fc_w;    wt = fcwT; K = 1024; bid -= 704; }
  else                { w = resid_w; wt = rswT; K = 768;  bid -= 960; }
  __shared__ float t[64][65];
  const int bk = (bid >> 4) << 6;
  const int bn = (bid & 15) << 6;
  const int rr = threadIdx.x >> 4;
  const int cc = (threadIdx.x & 15) << 2;
#pragma unroll
  for (int i = 0; i < 4; ++i) {
    int r = i * 16 + rr;
    float4 v = *reinterpret_cast<const float4*>(&w[(size_t)(bk + r) * 1024 + bn + cc]);
    t[r][cc] = v.x; t[r][cc + 1] = v.y; t[r][cc + 2] = v.z; t[r][cc + 3] = v.w;
  }
  __syncthreads();
#pragma unroll
  for (int i = 0; i < 4; ++i) {
    int n = i * 16 + rr;
    bf16x4 o;
    o[0] = (bf16_t)t[cc][n];     o[1] = (bf16_t)t[cc + 1][n];
    o[2] = (bf16_t)t[cc + 2][n]; o[3] = (bf16_t)t[cc + 3][n];
    *reinterpret_cast<bf16x4*>(&wt[(size_t)(bn + n) * K + bk + cc]) = o;
  }
}

// ---------------------------------------------------------------- V transpose + column sums
// Vp [B*LK, 1024] bf16 -> Vt [(b*16+h)*64 + d][LK] bf16 ; Vs[bh*64+d] += colsum
__global__ __launch_bounds__(256) void k_transpose_v(
    const bf16_t* __restrict__ Vp, bf16_t* __restrict__ Vt, float* __restrict__ Vs) {
  const int kt = blockIdx.x & 15;
  const int bh = blockIdx.x >> 4;
  const int b = bh >> 4, h = bh & 15;
  __shared__ unsigned short t[64][72];
  __shared__ float red[4][64];
#pragma unroll
  for (int i = 0; i < 2; ++i) {
    int cid = i * 256 + threadIdx.x;
    int r = cid >> 3, c = (cid & 7) * 8;
    uint4 v = *reinterpret_cast<const uint4*>(
        Vp + ((size_t)(b * 1024 + kt * 64 + r)) * 1024 + h * 64 + c);
    const unsigned short* pv = reinterpret_cast<const unsigned short*>(&v);
#pragma unroll
    for (int j = 0; j < 8; ++j) t[r][c + j] = pv[j];
  }
  __syncthreads();
#pragma unroll
  for (int i = 0; i < 2; ++i) {
    int cid = i * 256 + threadIdx.x;
    int d = cid >> 3, c = (cid & 7) * 8;
    unsigned short tmp[8];
#pragma unroll
    for (int j = 0; j < 8; ++j) tmp[j] = t[c + j][d];
    *reinterpret_cast<uint4*>(Vt + ((size_t)(bh * 64 + d)) * 1024 + kt * 64 + c) =
        *reinterpret_cast<uint4*>(tmp);
  }
  // partial column sums over the 64 local k-rows
  const int d = threadIdx.x & 63, seg = threadIdx.x >> 6;
  float s = 0.f;
#pragma unroll
  for (int i = 0; i < 16; ++i)
    s += (float)*(const bf16_t*)&t[seg * 16 + i][d];
  red[seg][d] = s;
  __syncthreads();
  if (threadIdx.x < 64)
    atomicAdd(&Vs[bh * 64 + threadIdx.x],
              red[0][threadIdx.x] + red[1][threadIdx.x] + red[2][threadIdx.x] + red[3][threadIdx.x]);
}

// ---------------------------------------------------------------- GEMM: C[M,N] = (A[M,K] * Bt[N,K]^T) * oscale, bf16 out
__global__ __launch_bounds__(256) void k_gemm_bt(
    const bf16_t* __restrict__ A, const bf16_t* __restrict__ Bt,
    bf16_t* __restrict__ C, int N, int K, float oscale) {
  __shared__ bf16_t As[128 * 32];
  __shared__ bf16_t Bs[128 * 32];
  // XCD-grouped block swizzle (gridDim multiple of 8)
  const int bpx = gridDim.x >> 3;
  const int wg = (blockIdx.x & 7) * bpx + (blockIdx.x >> 3);
  const int tn = N >> 7;
  const int m0 = (wg / tn) << 7;
  const int n0 = (wg % tn) << 7;
  const int lane = threadIdx.x & 63;
  const int wv = threadIdx.x >> 6;
  const int wr = (wv >> 1) * 64, wc = (wv & 1) * 64;
  const int lr = lane & 15, lk = lane >> 4;
  const int so0 = wv * 2048 + lane * 16;
  const int so1 = so0 + 1024;
  const int r0 = so0 >> 6, c0 = so0 & 63;
  const int r1 = so1 >> 6, c1 = so1 & 63;
  char* AsB = (char*)As;
  char* BsB = (char*)Bs;
  const char* Apc = (const char*)A;
  const char* Btc = (const char*)Bt;
  f32x4 zro = {0.f, 0.f, 0.f, 0.f};
  f32x4 acc[4][4];
#pragma unroll
  for (int i = 0; i < 4; ++i)
#pragma unroll
    for (int j = 0; j < 4; ++j) acc[i][j] = zro;

  for (int kt = 0; kt < K; kt += 32) {
    gl_lds16(AsB + wv * 2048,        Apc + ((size_t)(m0 + r0) * K + kt) * 2 + c0);
    gl_lds16(AsB + wv * 2048 + 1024, Apc + ((size_t)(m0 + r1) * K + kt) * 2 + c1);
    gl_lds16(BsB + wv * 2048,        Btc + ((size_t)(n0 + r0) * K + kt) * 2 + c0);
    gl_lds16(BsB + wv * 2048 + 1024, Btc + ((size_t)(n0 + r1) * K + kt) * 2 + c1);
    __syncthreads();
    bf16x8 af[4], bfr[4];
#pragma unroll
    for (int i = 0; i < 4; ++i)
      af[i] = *(const bf16x8*)(AsB + (wr + i * 16 + lr) * 64 + lk * 16);
#pragma unroll
    for (int j = 0; j < 4; ++j)
      bfr[j] = *(const bf16x8*)(BsB + (wc + j * 16 + lr) * 64 + lk * 16);
#pragma unroll
    for (int i = 0; i < 4; ++i)
#pragma unroll
      for (int j = 0; j < 4; ++j)
        acc[i][j] = __builtin_amdgcn_mfma_f32_16x16x32_bf16(af[i], bfr[j], acc[i][j], 0, 0, 0);
    __syncthreads();
  }
#pragma unroll
  for (int i = 0; i < 4; ++i)
#pragma unroll
    for (int j = 0; j < 4; ++j)
#pragma unroll
      for (int r = 0; r < 4; ++r)
        C[(size_t)(m0 + wr + i * 16 + lk * 4 + r) * N + n0 + wc + j * 16 + lr] =
            (bf16_t)(acc[i][j][r] * oscale);
}

// Y[M,N] f32 = A1*B1t^T + A2*B2t^T + bias
__global__ __launch_bounds__(256) void k_gemm_final(
    const bf16_t* __restrict__ A1, const bf16_t* __restrict__ B1t, int K1,
    const bf16_t* __restrict__ A2, const bf16_t* __restrict__ B2t, int K2,
    const float* __restrict__ bias, float* __restrict__ Y, int N) {
  __shared__ bf16_t As[128 * 32];
  __shared__ bf16_t Bs[128 * 32];
  const int bpx = gridDim.x >> 3;
  const int wg = (blockIdx.x & 7) * bpx + (blockIdx.x >> 3);
  const int tn = N >> 7;
  const int m0 = (wg / tn) << 7;
  const int n0 = (wg % tn) << 7;
  const int lane = threadIdx.x & 63;
  const int wv = threadIdx.x >> 6;
  const int wr = (wv >> 1) * 64, wc = (wv & 1) * 64;
  const int lr = lane & 15, lk = lane >> 4;
  const int so0 = wv * 2048 + lane * 16;
  const int so1 = so0 + 1024;
  const int r0 = so0 >> 6, c0 = so0 & 63;
  const int r1 = so1 >> 6, c1 = so1 & 63;
  char* AsB = (char*)As;
  char* BsB = (char*)Bs;
  f32x4 zro = {0.f, 0.f, 0.f, 0.f};
  f32x4 acc[4][4];
#pragma unroll
  for (int i = 0; i < 4; ++i)
#pragma unroll
    for (int j = 0; j < 4; ++j) acc[i][j] = zro;

  const bf16_t* Ap[2] = {A1, A2};
  const bf16_t* Bp[2] = {B1t, B2t};
  const int Kp_[2] = {K1, K2};
  for (int ph = 0; ph < 2; ++ph) {
    const char* Apc = (const char*)Ap[ph];
    const char* Btc = (const char*)Bp[ph];
    const int K = Kp_[ph];
    for (int kt = 0; kt < K; kt += 32) {
      gl_lds16(AsB + wv * 2048,        Apc + ((size_t)(m0 + r0) * K + kt) * 2 + c0);
      gl_lds16(AsB + wv * 2048 + 1024, Apc + ((size_t)(m0 + r1) * K + kt) * 2 + c1);
      gl_lds16(BsB + wv * 2048,        Btc + ((size_t)(n0 + r0) * K + kt) * 2 + c0);
      gl_lds16(BsB + wv * 2048 + 1024, Btc + ((size_t)(n0 + r1) * K + kt) * 2 + c1);
      __syncthreads();
      bf16x8 af[4], bfr[4];
#pragma unroll
      for (int i = 0; i < 4; ++i)
        af[i] = *(const bf16x8*)(AsB + (wr + i * 16 + lr) * 64 + lk * 16);
#pragma unroll
      for (int j = 0; j < 4; ++j)
        bfr[j] = *(const bf16x8*)(BsB + (wc + j * 16 + lr) * 64 + lk * 16);
#pragma unroll
      for (int i = 0; i < 4; ++i)
#pragma unroll
        for (int j = 0; j < 4; ++j)
          acc[i][j] = __builtin_amdgcn_mfma_f32_16x16x32_bf16(af[i], bfr[j], acc[i][j], 0, 0, 0);
      __syncthreads();
    }
  }
#pragma unroll
  for (int i = 0; i < 4; ++i)
#pragma unroll
    for (int j = 0; j < 4; ++j) {
      float bv = bias[n0 + wc + j * 16 + lr];
#pragma unroll
      for (int r = 0; r < 4; ++r)
        Y[(size_t)(m0 + wr + i * 16 + lk * 4 + r) * N + n0 + wc + j * 16 + lr] =
            acc[i][j][r] + bv;
    }
}

// ---------------------------------------------------------------- attention
// out_heads = (Vsum - softmax(QK^T/8) V) / 1023, bf16, layout [B*LQ, H*64]
// Q is pre-scaled by 1/8; softmax-lite (no max subtraction, deferred sum);
// double-buffered K/V with prefetch, one barrier per kt.
__global__ __launch_bounds__(256) void k_attn(
    const bf16_t* __restrict__ Qp, const bf16_t* __restrict__ Kp,
    const bf16_t* __restrict__ Vt, const float* __restrict__ Vsum,
    bf16_t* __restrict__ Aout) {
  // XCD-grouping: all 16 q-tiles of one (b,h) land on the same XCD
  const int bid = blockIdx.x;
  const int wgid = (bid & 7) * 256 + (bid >> 3);
  const int qt = wgid & 15;
  const int bh = wgid >> 4;
  const int b = bh >> 4, h = bh & 15;
  __shared__ bf16_t Qs[64 * 64];
  __shared__ bf16_t Ks[2][64 * 64];
  __shared__ bf16_t Vs[2][64 * 64];
  __shared__ bf16_t Ps[4][16 * 64];
  const int lane = threadIdx.x & 63;
  const int wv = threadIdx.x >> 6;
  const int lr = lane & 15, lk = lane >> 4;
  char* QsB = (char*)Qs;
  char* PsB = (char*)(&Ps[wv][0]);

  const int o0 = wv * 2048 + lane * 16;
  const int o1 = o0 + 1024;
  const int row0 = o0 >> 7, row1 = o1 >> 7;
  const int sc0 = ((((o0 >> 4) & 7) ^ (row0 & 7)) << 4);
  const int sc1 = ((((o1 >> 4) & 7) ^ (row1 & 7)) << 4);

  const char* Ksrc0 = (const char*)(Kp + ((size_t)(b * 1024 + row0)) * 1024 + h * 64) + sc0;
  const char* Ksrc1 = (const char*)(Kp + ((size_t)(b * 1024 + row1)) * 1024 + h * 64) + sc1;
  const char* Vsrc0 = (const char*)(Vt + ((size_t)(bh * 64 + row0)) * 1024) + sc0;
  const char* Vsrc1 = (const char*)(Vt + ((size_t)(bh * 64 + row1)) * 1024) + sc1;

  // prologue: stage Q and K/V tile 0
  gl_lds16(QsB + wv * 2048,
           (const char*)(Qp + ((size_t)(b * 1024 + qt * 64 + row0)) * 1024 + h * 64) + sc0);
  gl_lds16(QsB + wv * 2048 + 1024,
           (const char*)(Qp + ((size_t)(b * 1024 + qt * 64 + row1)) * 1024 + h * 64) + sc1);
  gl_lds16((char*)&Ks[0][0] + wv * 2048,        Ksrc0);
  gl_lds16((char*)&Ks[0][0] + wv * 2048 + 1024, Ksrc1);
  gl_lds16((char*)&Vs[0][0] + wv * 2048,        Vsrc0);
  gl_lds16((char*)&Vs[0][0] + wv * 2048 + 1024, Vsrc1);
  __syncthreads();

  bf16x8 qa[2];
#pragma unroll
  for (int ks = 0; ks < 2; ++ks)
    qa[ks] = *(const bf16x8*)(QsB + SWZ128(wv * 16 + lr, ks * 64 + lk * 16));

  f32x4 zro = {0.f, 0.f, 0.f, 0.f};
  f32x4 oacc[4];
#pragma unroll
  for (int g = 0; g < 4; ++g) oacc[g] = zro;
  float ps[4] = {0.f, 0.f, 0.f, 0.f};

  for (int kt = 0; kt < 16; ++kt) {
    const int cur = kt & 1;
    char* KsB = (char*)&Ks[cur][0];
    char* VsB = (char*)&Vs[cur][0];
    if (kt < 15) {  // prefetch next tile into the other buffer
      char* KsN = (char*)&Ks[cur ^ 1][0];
      char* VsN = (char*)&Vs[cur ^ 1][0];
      const size_t koff = (size_t)(kt + 1) * 64 * 2048;  // 64 rows * 1024 cols * 2B
      const size_t voff = (size_t)(kt + 1) * 128;        // 64 cols * 2B
      gl_lds16(KsN + wv * 2048,        Ksrc0 + koff);
      gl_lds16(KsN + wv * 2048 + 1024, Ksrc1 + koff);
      gl_lds16(VsN + wv * 2048,        Vsrc0 + voff);
      gl_lds16(VsN + wv * 2048 + 1024, Vsrc1 + voff);
    }

    // S = (Q/8) K^T
    f32x4 sacc[4];
#pragma unroll
    for (int g = 0; g < 4; ++g) sacc[g] = zro;
#pragma unroll
    for (int ks = 0; ks < 2; ++ks)
#pragma unroll
      for (int g = 0; g < 4; ++g) {
        bf16x8 kb = *(const bf16x8*)(KsB + SWZ128(g * 16 + lr, ks * 64 + lk * 16));
        sacc[g] = __builtin_amdgcn_mfma_f32_16x16x32_bf16(qa[ks], kb, sacc[g], 0, 0, 0);
      }

    // softmax-lite: p = exp(s), accumulate per-thread partial sums, store P
#pragma unroll
    for (int g = 0; g < 4; ++g)
#pragma unroll
      for (int r = 0; r < 4; ++r) {
        float p = __expf(sacc[g][r]);
        ps[r] += p;
        *(bf16_t*)(PsB + SWZ128(lk * 4 + r, (g * 16 + lr) * 2)) = (bf16_t)p;
      }

    // O += P V
#pragma unroll
    for (int ks = 0; ks < 2; ++ks) {
      bf16x8 pa = *(const bf16x8*)(PsB + SWZ128(lr, ks * 64 + lk * 16));
#pragma unroll
      for (int gd = 0; gd < 4; ++gd) {
        bf16x8 vb = *(const bf16x8*)(VsB + SWZ128(gd * 16 + lr, ks * 64 + lk * 16));
        oacc[gd] = __builtin_amdgcn_mfma_f32_16x16x32_bf16(pa, vb, oacc[gd], 0, 0, 0);
      }
    }
    __syncthreads();  // drains prefetch vmcnt + syncs buffer reuse
  }

  // epilogue: reduce partial sums over the 16-lane groups (bits 0..3 of lane)
  float lsum[4];
#pragma unroll
  for (int r = 0; r < 4; ++r) {
    float s = ps[r];
    s += __shfl_xor(s, 1, 64);
    s += __shfl_xor(s, 2, 64);
    s += __shfl_xor(s, 4, 64);
    s += __shfl_xor(s, 8, 64);
    lsum[r] = s;
  }
#pragma unroll
  for (int gd = 0; gd < 4; ++gd)
#pragma unroll
    for (int r = 0; r < 4; ++r) {
      int d = gd * 16 + lr;
      int qrow = qt * 64 + wv * 16 + lk * 4 + r;
      float attnv = oacc[gd][r] / lsum[r];
      float val = (Vsum[bh * 64 + d] - attnv) * (1.0f / 1023.0f);
      Aout[((size_t)(b * 1024 + qrow)) * 1024 + h * 64 + d] = (bf16_t)val;
    }
}

// ---------------------------------------------------------------- layernorm
__global__ __launch_bounds__(256) void k_ln(
    const float* __restrict__ Y, const float* __restrict__ gamma,
    const float* __restrict__ beta, float* __restrict__ out) {
  const int row = blockIdx.x, tid = threadIdx.x;
  const float4 x = reinterpret_cast<const float4*>(Y + (size_t)row * 1024)[tid];
  float s = x.x + x.y + x.z + x.w;
  float q = x.x * x.x + x.y * x.y + x.z * x.z + x.w * x.w;
#pragma unroll
  for (int off = 32; off > 0; off >>= 1) {
    s += __shfl_xor(s, off, 64);
    q += __shfl_xor(q, off, 64);
  }
  __shared__ float ss[4], qs[4];
  if ((tid & 63) == 0) { ss[tid >> 6] = s; qs[tid >> 6] = q; }
  __syncthreads();
  s = ss[0] + ss[1] + ss[2] + ss[3];
  q = qs[0] + qs[1] + qs[2] + qs[3];
  float mean = s * (1.f / 1024.f);
  float var = q * (1.f / 1024.f) - mean * mean;
  float rstd = rsqrtf(var + 1e-5f);
  float4 g = reinterpret_cast<const float4*>(gamma)[tid];
  float4 bt = reinterpret_cast<const float4*>(beta)[tid];
  float4 o;
  o.x = (x.x - mean) * rstd * g.x + bt.x;
  o.y = (x.y - mean) * rstd * g.y + bt.y;
  o.z = (x.z - mean) * rstd * g.z + bt.z;
  o.w = (x.w - mean) * rstd * g.w + bt.w;
  reinterpret_cast<float4*>(out + (size_t)row * 1024)[tid] = o;
}

// ---------------------------------------------------------------- launch
extern "C" void kernel_launch(void* const* d_in, const int* in_sizes, int n_in,
                              void* d_out, int out_size, void* d_ws, size_t ws_size,
                              hipStream_t stream) {
  (void)in_sizes; (void)n_in; (void)out_size;
  const float* q       = (const float*)d_in[0];
  const float* k       = (const float*)d_in[1];
  const float* v       = (const float*)d_in[2];
  const float* w_qs    = (const float*)d_in[3];
  const float* w_ks    = (const float*)d_in[4];
  const float* w_vs    = (const float*)d_in[5];
  const float* fc_w    = (const float*)d_in[6];
  const float* resid_w = (const float*)d_in[7];
  const float* resid_b = (const float*)d_in[8];
  const float* ln_g    = (const float*)d_in[9];
  const float* ln_b    = (const float*)d_in[10];
  float* out = (float*)d_out;
  char* ws = (char*)d_ws;

  if (ws_size < (size_t)122716160) return;  // need ~117 MB

  bf16_t* qb   = (bf16_t*)(ws + 0);
  bf16_t* kb   = (bf16_t*)(ws + 12582912);
  bf16_t* vb   = (bf16_t*)(ws + 29360128);
  float*  Y    = (float*)(ws + 12582912);   // aliases kb+vb (dead after projections)
  bf16_t* wqsT = (bf16_t*)(ws + 46137344);
  bf16_t* wksT = (bf16_t*)(ws + 47710208);
  bf16_t* wvsT = (bf16_t*)(ws + 49807360);
  bf16_t* fcwT = (bf16_t*)(ws + 51904512);
  bf16_t* rswT = (bf16_t*)(ws + 54001664);
  bf16_t* Qp   = (bf16_t*)(ws + 55574528);
  bf16_t* Kp   = (bf16_t*)(ws + 72351744);
  bf16_t* Vp   = (bf16_t*)(ws + 89128960);
  bf16_t* Aout = (bf16_t*)(ws + 89128960);  // aliases Vp (dead after transpose_v)
  bf16_t* VtT  = (bf16_t*)(ws + 105906176);
  float*  Vsm  = (float*)(ws + 122683392);

  k_convert_all<<<2048, 256, 0, stream>>>(q, k, v, qb, kb, vb, Vsm);
  k_transpose_all<<<1152, 256, 0, stream>>>(w_qs, w_ks, w_vs, fc_w, resid_w,
                                            wqsT, wksT, wvsT, fcwT, rswT);
  k_gemm_bt<<<512, 256, 0, stream>>>(qb, wqsT, Qp, 1024, 768, 0.125f);
  k_gemm_bt<<<512, 256, 0, stream>>>(kb, wksT, Kp, 1024, 1024, 1.0f);
  k_gemm_bt<<<512, 256, 0, stream>>>(vb, wvsT, Vp, 1024, 1024, 1.0f);
  k_transpose_v<<<2048, 256, 0, stream>>>(Vp, VtT, Vsm);
  k_attn<<<2048, 256, 0, stream>>>(Qp, Kp, VtT, Vsm, Aout);
  k_gemm_final<<<512, 256, 0, stream>>>(Aout, fcwT, 1024, qb, rswT, 768, resid_b, Y, 1024);
  k_ln<<<8192, 256, 0, stream>>>(Y, ln_g, ln_b, out);
}

// Round 4
// 235.849 us; speedup vs baseline: 1.3348x; 1.0431x over previous
//
#include <hip/hip_runtime.h>

typedef __bf16 bf16_t;
typedef __bf16 bf16x8 __attribute__((ext_vector_type(8)));
typedef __bf16 bf16x4 __attribute__((ext_vector_type(4)));
typedef float  f32x4  __attribute__((ext_vector_type(4)));
typedef short  short4v __attribute__((ext_vector_type(4)));

#if __has_builtin(__builtin_amdgcn_mfma_f32_16x16x16bf16_1k)
#define HAS_1K 1
#else
#define HAS_1K 0
#endif

#define DEVFN __device__ __forceinline__

DEVFN void gl_lds16(void* lds_base, const void* gsrc) {
  __builtin_amdgcn_global_load_lds(
      (const __attribute__((address_space(1))) void*)gsrc,
      (__attribute__((address_space(3))) void*)lds_base, 16, 0, 0);
}

// swizzled byte offset within a [rows][128B] LDS tile: chunk c of row r lives at c^(r&7)
#define SWZ128(row, bo) (((row) << 7) + ((((bo) >> 4) ^ ((row) & 7)) << 4) + ((bo) & 15))

// ---------------------------------------------------------------- fused converts (+ Vsum zero)
__global__ __launch_bounds__(256) void k_convert_all(
    const float* __restrict__ q, const float* __restrict__ k, const float* __restrict__ v,
    bf16_t* __restrict__ qb, bf16_t* __restrict__ kb, bf16_t* __restrict__ vb,
    float* __restrict__ Vs) {
  if (blockIdx.x == 0) {
    // zero ALL of Vsum (8192 floats) — atomicAdd target, re-zeroed every call
    for (int j = threadIdx.x; j < 8192; j += 256) Vs[j] = 0.f;
  }
  const int NQ = 1572864, NK = 2097152, NT = NQ + 2 * NK;
  int stride = gridDim.x * 256;
  for (int i = blockIdx.x * 256 + threadIdx.x; i < NT; i += stride) {
    const float* src; bf16_t* dst; int off;
    if (i < NQ)           { src = q; dst = qb; off = i; }
    else if (i < NQ + NK) { src = k; dst = kb; off = i - NQ; }
    else                  { src = v; dst = vb; off = i - NQ - NK; }
    float4 vv = reinterpret_cast<const float4*>(src)[off];
    bf16x4 o;
    o[0] = (bf16_t)vv.x; o[1] = (bf16_t)vv.y; o[2] = (bf16_t)vv.z; o[3] = (bf16_t)vv.w;
    reinterpret_cast<bf16x4*>(dst)[off] = o;
  }
}

// ---------------------------------------------------------------- fused weight transposes
__global__ __launch_bounds__(256) void k_transpose_all(
    const float* __restrict__ w_qs, const float* __restrict__ w_ks,
    const float* __restrict__ w_vs, const float* __restrict__ fc_w,
    const float* __restrict__ resid_w,
    bf16_t* __restrict__ wqsT, bf16_t* __restrict__ wksT, bf16_t* __restrict__ wvsT,
    bf16_t* __restrict__ fcwT, bf16_t* __restrict__ rswT) {
  int bid = blockIdx.x;
  const float* w; bf16_t* wt; int K;
  if (bid < 192)      { w = w_qs;    wt = wqsT; K = 768; }
  else if (bid < 448) { w = w_ks;    wt = wksT; K = 1024; bid -= 192; }
  else if (bid < 704) { w = w_vs;    wt = wvsT; K = 1024; bid -= 448; }
  else if (bid < 960) { w = fc_w;    wt = fcwT; K = 1024; bid -= 704; }
  else                { w = resid_w; wt = rswT; K = 768;  bid -= 960; }
  __shared__ float t[64][65];
  const int bk = (bid >> 4) << 6;
  const int bn = (bid & 15) << 6;
  const int rr = threadIdx.x >> 4;
  const int cc = (threadIdx.x & 15) << 2;
#pragma unroll
  for (int i = 0; i < 4; ++i) {
    int r = i * 16 + rr;
    float4 v = *reinterpret_cast<const float4*>(&w[(size_t)(bk + r) * 1024 + bn + cc]);
    t[r][cc] = v.x; t[r][cc + 1] = v.y; t[r][cc + 2] = v.z; t[r][cc + 3] = v.w;
  }
  __syncthreads();
#pragma unroll
  for (int i = 0; i < 4; ++i) {
    int n = i * 16 + rr;
    bf16x4 o;
    o[0] = (bf16_t)t[cc][n];     o[1] = (bf16_t)t[cc + 1][n];
    o[2] = (bf16_t)t[cc + 2][n]; o[3] = (bf16_t)t[cc + 3][n];
    *reinterpret_cast<bf16x4*>(&wt[(size_t)(bn + n) * K + bk + cc]) = o;
  }
}

// ---------------------------------------------------------------- V transpose + column sums
__global__ __launch_bounds__(256) void k_transpose_v(
    const bf16_t* __restrict__ Vp, bf16_t* __restrict__ Vt, float* __restrict__ Vs) {
  const int kt = blockIdx.x & 15;
  const int bh = blockIdx.x >> 4;
  const int b = bh >> 4, h = bh & 15;
  __shared__ unsigned short t[64][72];
  __shared__ float red[4][64];
#pragma unroll
  for (int i = 0; i < 2; ++i) {
    int cid = i * 256 + threadIdx.x;
    int r = cid >> 3, c = (cid & 7) * 8;
    uint4 v = *reinterpret_cast<const uint4*>(
        Vp + ((size_t)(b * 1024 + kt * 64 + r)) * 1024 + h * 64 + c);
    const unsigned short* pv = reinterpret_cast<const unsigned short*>(&v);
#pragma unroll
    for (int j = 0; j < 8; ++j) t[r][c + j] = pv[j];
  }
  __syncthreads();
#pragma unroll
  for (int i = 0; i < 2; ++i) {
    int cid = i * 256 + threadIdx.x;
    int d = cid >> 3, c = (cid & 7) * 8;
    unsigned short tmp[8];
#pragma unroll
    for (int j = 0; j < 8; ++j) tmp[j] = t[c + j][d];
    *reinterpret_cast<uint4*>(Vt + ((size_t)(bh * 64 + d)) * 1024 + kt * 64 + c) =
        *reinterpret_cast<uint4*>(tmp);
  }
  const int d = threadIdx.x & 63, seg = threadIdx.x >> 6;
  float s = 0.f;
#pragma unroll
  for (int i = 0; i < 16; ++i)
    s += (float)*(const bf16_t*)&t[seg * 16 + i][d];
  red[seg][d] = s;
  __syncthreads();
  if (threadIdx.x < 64)
    atomicAdd(&Vs[bh * 64 + threadIdx.x],
              red[0][threadIdx.x] + red[1][threadIdx.x] + red[2][threadIdx.x] + red[3][threadIdx.x]);
}

// ---------------------------------------------------------------- GEMM: C[M,N] = (A[M,K] * Bt[N,K]^T) * oscale, bf16 out
__global__ __launch_bounds__(256) void k_gemm_bt(
    const bf16_t* __restrict__ A, const bf16_t* __restrict__ Bt,
    bf16_t* __restrict__ C, int N, int K, float oscale) {
  __shared__ bf16_t As[128 * 32];
  __shared__ bf16_t Bs[128 * 32];
  const int bpx = gridDim.x >> 3;
  const int wg = (blockIdx.x & 7) * bpx + (blockIdx.x >> 3);
  const int tn = N >> 7;
  const int m0 = (wg / tn) << 7;
  const int n0 = (wg % tn) << 7;
  const int lane = threadIdx.x & 63;
  const int wv = threadIdx.x >> 6;
  const int wr = (wv >> 1) * 64, wc = (wv & 1) * 64;
  const int lr = lane & 15, lk = lane >> 4;
  const int so0 = wv * 2048 + lane * 16;
  const int so1 = so0 + 1024;
  const int r0 = so0 >> 6, c0 = so0 & 63;
  const int r1 = so1 >> 6, c1 = so1 & 63;
  char* AsB = (char*)As;
  char* BsB = (char*)Bs;
  const char* Apc = (const char*)A;
  const char* Btc = (const char*)Bt;
  f32x4 zro = {0.f, 0.f, 0.f, 0.f};
  f32x4 acc[4][4];
#pragma unroll
  for (int i = 0; i < 4; ++i)
#pragma unroll
    for (int j = 0; j < 4; ++j) acc[i][j] = zro;

  for (int kt = 0; kt < K; kt += 32) {
    gl_lds16(AsB + wv * 2048,        Apc + ((size_t)(m0 + r0) * K + kt) * 2 + c0);
    gl_lds16(AsB + wv * 2048 + 1024, Apc + ((size_t)(m0 + r1) * K + kt) * 2 + c1);
    gl_lds16(BsB + wv * 2048,        Btc + ((size_t)(n0 + r0) * K + kt) * 2 + c0);
    gl_lds16(BsB + wv * 2048 + 1024, Btc + ((size_t)(n0 + r1) * K + kt) * 2 + c1);
    __syncthreads();
    bf16x8 af[4], bfr[4];
#pragma unroll
    for (int i = 0; i < 4; ++i)
      af[i] = *(const bf16x8*)(AsB + (wr + i * 16 + lr) * 64 + lk * 16);
#pragma unroll
    for (int j = 0; j < 4; ++j)
      bfr[j] = *(const bf16x8*)(BsB + (wc + j * 16 + lr) * 64 + lk * 16);
#pragma unroll
    for (int i = 0; i < 4; ++i)
#pragma unroll
      for (int j = 0; j < 4; ++j)
        acc[i][j] = __builtin_amdgcn_mfma_f32_16x16x32_bf16(af[i], bfr[j], acc[i][j], 0, 0, 0);
    __syncthreads();
  }
#pragma unroll
  for (int i = 0; i < 4; ++i)
#pragma unroll
    for (int j = 0; j < 4; ++j)
#pragma unroll
      for (int r = 0; r < 4; ++r)
        C[(size_t)(m0 + wr + i * 16 + lk * 4 + r) * N + n0 + wc + j * 16 + lr] =
            (bf16_t)(acc[i][j][r] * oscale);
}

// Y[M,N] f32 = A1*B1t^T + A2*B2t^T + bias
__global__ __launch_bounds__(256) void k_gemm_final(
    const bf16_t* __restrict__ A1, const bf16_t* __restrict__ B1t, int K1,
    const bf16_t* __restrict__ A2, const bf16_t* __restrict__ B2t, int K2,
    const float* __restrict__ bias, float* __restrict__ Y, int N) {
  __shared__ bf16_t As[128 * 32];
  __shared__ bf16_t Bs[128 * 32];
  const int bpx = gridDim.x >> 3;
  const int wg = (blockIdx.x & 7) * bpx + (blockIdx.x >> 3);
  const int tn = N >> 7;
  const int m0 = (wg / tn) << 7;
  const int n0 = (wg % tn) << 7;
  const int lane = threadIdx.x & 63;
  const int wv = threadIdx.x >> 6;
  const int wr = (wv >> 1) * 64, wc = (wv & 1) * 64;
  const int lr = lane & 15, lk = lane >> 4;
  const int so0 = wv * 2048 + lane * 16;
  const int so1 = so0 + 1024;
  const int r0 = so0 >> 6, c0 = so0 & 63;
  const int r1 = so1 >> 6, c1 = so1 & 63;
  char* AsB = (char*)As;
  char* BsB = (char*)Bs;
  f32x4 zro = {0.f, 0.f, 0.f, 0.f};
  f32x4 acc[4][4];
#pragma unroll
  for (int i = 0; i < 4; ++i)
#pragma unroll
    for (int j = 0; j < 4; ++j) acc[i][j] = zro;

  const bf16_t* Ap[2] = {A1, A2};
  const bf16_t* Bp[2] = {B1t, B2t};
  const int Kp_[2] = {K1, K2};
  for (int ph = 0; ph < 2; ++ph) {
    const char* Apc = (const char*)Ap[ph];
    const char* Btc = (const char*)Bp[ph];
    const int K = Kp_[ph];
    for (int kt = 0; kt < K; kt += 32) {
      gl_lds16(AsB + wv * 2048,        Apc + ((size_t)(m0 + r0) * K + kt) * 2 + c0);
      gl_lds16(AsB + wv * 2048 + 1024, Apc + ((size_t)(m0 + r1) * K + kt) * 2 + c1);
      gl_lds16(BsB + wv * 2048,        Btc + ((size_t)(n0 + r0) * K + kt) * 2 + c0);
      gl_lds16(BsB + wv * 2048 + 1024, Btc + ((size_t)(n0 + r1) * K + kt) * 2 + c1);
      __syncthreads();
      bf16x8 af[4], bfr[4];
#pragma unroll
      for (int i = 0; i < 4; ++i)
        af[i] = *(const bf16x8*)(AsB + (wr + i * 16 + lr) * 64 + lk * 16);
#pragma unroll
      for (int j = 0; j < 4; ++j)
        bfr[j] = *(const bf16x8*)(BsB + (wc + j * 16 + lr) * 64 + lk * 16);
#pragma unroll
      for (int i = 0; i < 4; ++i)
#pragma unroll
        for (int j = 0; j < 4; ++j)
          acc[i][j] = __builtin_amdgcn_mfma_f32_16x16x32_bf16(af[i], bfr[j], acc[i][j], 0, 0, 0);
      __syncthreads();
    }
  }
#pragma unroll
  for (int i = 0; i < 4; ++i)
#pragma unroll
    for (int j = 0; j < 4; ++j) {
      float bv = bias[n0 + wc + j * 16 + lr];
#pragma unroll
      for (int r = 0; r < 4; ++r)
        Y[(size_t)(m0 + wr + i * 16 + lk * 4 + r) * N + n0 + wc + j * 16 + lr] =
            acc[i][j][r] + bv;
    }
}

// ---------------------------------------------------------------- attention
// out = (Vsum - softmax(QK^T/8) V) / 1023.  Q pre-scaled by 1/8; softmax-lite.
// Swapped QK^T: sacc[g][r] = S[q=lr][k=g*16+lk*4+r] — lane-local P row slices,
// which IS the A-fragment layout of mfma_16x16x16_bf16 → PV entirely in-register.
__global__ __launch_bounds__(256) void k_attn(
    const bf16_t* __restrict__ Qp, const bf16_t* __restrict__ Kp,
    const bf16_t* __restrict__ Vt, const float* __restrict__ Vsum,
    bf16_t* __restrict__ Aout) {
  const int bid = blockIdx.x;
  const int wgid = (bid & 7) * 256 + (bid >> 3);   // XCD-grouping
  const int qt = wgid & 15;
  const int bh = wgid >> 4;
  const int b = bh >> 4, h = bh & 15;
  __shared__ bf16_t Qs[64 * 64];
  __shared__ bf16_t Ks[2][64 * 64];
  __shared__ bf16_t Vs[2][64 * 64];
#if !HAS_1K
  __shared__ bf16_t Ps[4][16 * 64];
#endif
  const int lane = threadIdx.x & 63;
  const int wv = threadIdx.x >> 6;
  const int lr = lane & 15, lk = lane >> 4;
  char* QsB = (char*)Qs;

  const int o0 = wv * 2048 + lane * 16;
  const int o1 = o0 + 1024;
  const int row0 = o0 >> 7, row1 = o1 >> 7;
  const int sc0 = ((((o0 >> 4) & 7) ^ (row0 & 7)) << 4);
  const int sc1 = ((((o1 >> 4) & 7) ^ (row1 & 7)) << 4);

  const char* Ksrc0 = (const char*)(Kp + ((size_t)(b * 1024 + row0)) * 1024 + h * 64) + sc0;
  const char* Ksrc1 = (const char*)(Kp + ((size_t)(b * 1024 + row1)) * 1024 + h * 64) + sc1;
  const char* Vsrc0 = (const char*)(Vt + ((size_t)(bh * 64 + row0)) * 1024) + sc0;
  const char* Vsrc1 = (const char*)(Vt + ((size_t)(bh * 64 + row1)) * 1024) + sc1;

  gl_lds16(QsB + wv * 2048,
           (const char*)(Qp + ((size_t)(b * 1024 + qt * 64 + row0)) * 1024 + h * 64) + sc0);
  gl_lds16(QsB + wv * 2048 + 1024,
           (const char*)(Qp + ((size_t)(b * 1024 + qt * 64 + row1)) * 1024 + h * 64) + sc1);
  gl_lds16((char*)&Ks[0][0] + wv * 2048,        Ksrc0);
  gl_lds16((char*)&Ks[0][0] + wv * 2048 + 1024, Ksrc1);
  gl_lds16((char*)&Vs[0][0] + wv * 2048,        Vsrc0);
  gl_lds16((char*)&Vs[0][0] + wv * 2048 + 1024, Vsrc1);
  __syncthreads();

  bf16x8 qa[2];
#pragma unroll
  for (int ks = 0; ks < 2; ++ks)
    qa[ks] = *(const bf16x8*)(QsB + SWZ128(wv * 16 + lr, ks * 64 + lk * 16));

  f32x4 zro = {0.f, 0.f, 0.f, 0.f};
  f32x4 oacc[4];
#pragma unroll
  for (int g = 0; g < 4; ++g) oacc[g] = zro;
  float ps = 0.f;   // partial row-sum for q = lr (lane-local)

  for (int kt = 0; kt < 16; ++kt) {
    const int cur = kt & 1;
    char* KsB = (char*)&Ks[cur][0];
    char* VsB = (char*)&Vs[cur][0];
    if (kt < 15) {
      char* KsN = (char*)&Ks[cur ^ 1][0];
      char* VsN = (char*)&Vs[cur ^ 1][0];
      const size_t koff = (size_t)(kt + 1) * 64 * 2048;
      const size_t voff = (size_t)(kt + 1) * 128;
      gl_lds16(KsN + wv * 2048,        Ksrc0 + koff);
      gl_lds16(KsN + wv * 2048 + 1024, Ksrc1 + koff);
      gl_lds16(VsN + wv * 2048,        Vsrc0 + voff);
      gl_lds16(VsN + wv * 2048 + 1024, Vsrc1 + voff);
    }

    // S^T = K Q^T : sacc[g][r] = S[q=lr][k = g*16 + lk*4 + r]
    f32x4 sacc[4];
#pragma unroll
    for (int g = 0; g < 4; ++g) sacc[g] = zro;
#pragma unroll
    for (int ks = 0; ks < 2; ++ks)
#pragma unroll
      for (int g = 0; g < 4; ++g) {
        bf16x8 kb = *(const bf16x8*)(KsB + SWZ128(g * 16 + lr, ks * 64 + lk * 16));
        sacc[g] = __builtin_amdgcn_mfma_f32_16x16x32_bf16(kb, qa[ks], sacc[g], 0, 0, 0);
      }

#if HAS_1K
    // exp + pack P in-register (A-frag of 16x16x16: lane holds P[q=lr][k=lk*4+j])
    short4v pa_s[4];
#pragma unroll
    for (int g = 0; g < 4; ++g) {
      bf16x4 pw;
#pragma unroll
      for (int r = 0; r < 4; ++r) {
        float p = __expf(sacc[g][r]);
        ps += p;
        pw[r] = (bf16_t)p;
      }
      pa_s[g] = __builtin_bit_cast(short4v, pw);
    }
    // O += P V : 16x16x16 MFMAs, V tile read as b64 fragments
#pragma unroll
    for (int g = 0; g < 4; ++g)
#pragma unroll
      for (int gd = 0; gd < 4; ++gd) {
        short4v vbv = *(const short4v*)(VsB + SWZ128(gd * 16 + lr, g * 32 + lk * 8));
        oacc[gd] = __builtin_amdgcn_mfma_f32_16x16x16bf16_1k(pa_s[g], vbv, oacc[gd], 0, 0, 0);
      }
#else
    // fallback: stage P through LDS (row q = lr), then x32 PV as before
    {
      char* PsB = (char*)(&Ps[wv][0]);
#pragma unroll
      for (int g = 0; g < 4; ++g)
#pragma unroll
        for (int r = 0; r < 4; ++r) {
          float p = __expf(sacc[g][r]);
          ps += p;
          *(bf16_t*)(PsB + SWZ128(lr, (g * 16 + lk * 4 + r) * 2)) = (bf16_t)p;
        }
#pragma unroll
      for (int ks = 0; ks < 2; ++ks) {
        bf16x8 pa = *(const bf16x8*)(PsB + SWZ128(lr, ks * 64 + lk * 16));
#pragma unroll
        for (int gd = 0; gd < 4; ++gd) {
          bf16x8 vbv = *(const bf16x8*)(VsB + SWZ128(gd * 16 + lr, ks * 64 + lk * 16));
          oacc[gd] = __builtin_amdgcn_mfma_f32_16x16x32_bf16(pa, vbv, oacc[gd], 0, 0, 0);
        }
      }
    }
#endif
    __syncthreads();
  }

  // epilogue: total row-sums. ps holds partial for q=lr; reduce across lk lanes.
  float stot = ps;
  stot += __shfl_xor(stot, 16, 64);
  stot += __shfl_xor(stot, 32, 64);
  // redistribute: output rows are q = lk*4 + r; lane (lk*4+r) holds that q's sum
  float lsum_q[4];
#pragma unroll
  for (int r = 0; r < 4; ++r) lsum_q[r] = __shfl(stot, lk * 4 + r, 64);

#pragma unroll
  for (int gd = 0; gd < 4; ++gd)
#pragma unroll
    for (int r = 0; r < 4; ++r) {
      int d = gd * 16 + lr;
      int qrow = qt * 64 + wv * 16 + lk * 4 + r;
      float attnv = oacc[gd][r] / lsum_q[r];
      float val = (Vsum[bh * 64 + d] - attnv) * (1.0f / 1023.0f);
      Aout[((size_t)(b * 1024 + qrow)) * 1024 + h * 64 + d] = (bf16_t)val;
    }
}

// ---------------------------------------------------------------- layernorm
__global__ __launch_bounds__(256) void k_ln(
    const float* __restrict__ Y, const float* __restrict__ gamma,
    const float* __restrict__ beta, float* __restrict__ out) {
  const int row = blockIdx.x, tid = threadIdx.x;
  const float4 x = reinterpret_cast<const float4*>(Y + (size_t)row * 1024)[tid];
  float s = x.x + x.y + x.z + x.w;
  float q = x.x * x.x + x.y * x.y + x.z * x.z + x.w * x.w;
#pragma unroll
  for (int off = 32; off > 0; off >>= 1) {
    s += __shfl_xor(s, off, 64);
    q += __shfl_xor(q, off, 64);
  }
  __shared__ float ss[4], qs[4];
  if ((tid & 63) == 0) { ss[tid >> 6] = s; qs[tid >> 6] = q; }
  __syncthreads();
  s = ss[0] + ss[1] + ss[2] + ss[3];
  q = qs[0] + qs[1] + qs[2] + qs[3];
  float mean = s * (1.f / 1024.f);
  float var = q * (1.f / 1024.f) - mean * mean;
  float rstd = rsqrtf(var + 1e-5f);
  float4 g = reinterpret_cast<const float4*>(gamma)[tid];
  float4 bt = reinterpret_cast<const float4*>(beta)[tid];
  float4 o;
  o.x = (x.x - mean) * rstd * g.x + bt.x;
  o.y = (x.y - mean) * rstd * g.y + bt.y;
  o.z = (x.z - mean) * rstd * g.z + bt.z;
  o.w = (x.w - mean) * rstd * g.w + bt.w;
  reinterpret_cast<float4*>(out + (size_t)row * 1024)[tid] = o;
}

// ---------------------------------------------------------------- launch
extern "C" void kernel_launch(void* const* d_in, const int* in_sizes, int n_in,
                              void* d_out, int out_size, void* d_ws, size_t ws_size,
                              hipStream_t stream) {
  (void)in_sizes; (void)n_in; (void)out_size;
  const float* q       = (const float*)d_in[0];
  const float* k       = (const float*)d_in[1];
  const float* v       = (const float*)d_in[2];
  const float* w_qs    = (const float*)d_in[3];
  const float* w_ks    = (const float*)d_in[4];
  const float* w_vs    = (const float*)d_in[5];
  const float* fc_w    = (const float*)d_in[6];
  const float* resid_w = (const float*)d_in[7];
  const float* resid_b = (const float*)d_in[8];
  const float* ln_g    = (const float*)d_in[9];
  const float* ln_b    = (const float*)d_in[10];
  float* out = (float*)d_out;
  char* ws = (char*)d_ws;

  if (ws_size < (size_t)122716160) return;  // need ~117 MB

  bf16_t* qb   = (bf16_t*)(ws + 0);
  bf16_t* kb   = (bf16_t*)(ws + 12582912);
  bf16_t* vb   = (bf16_t*)(ws + 29360128);
  float*  Y    = (float*)(ws + 12582912);   // aliases kb+vb (dead after projections)
  bf16_t* wqsT = (bf16_t*)(ws + 46137344);
  bf16_t* wksT = (bf16_t*)(ws + 47710208);
  bf16_t* wvsT = (bf16_t*)(ws + 49807360);
  bf16_t* fcwT = (bf16_t*)(ws + 51904512);
  bf16_t* rswT = (bf16_t*)(ws + 54001664);
  bf16_t* Qp   = (bf16_t*)(ws + 55574528);
  bf16_t* Kp   = (bf16_t*)(ws + 72351744);
  bf16_t* Vp   = (bf16_t*)(ws + 89128960);
  bf16_t* Aout = (bf16_t*)(ws + 89128960);  // aliases Vp (dead after transpose_v)
  bf16_t* VtT  = (bf16_t*)(ws + 105906176);
  float*  Vsm  = (float*)(ws + 122683392);

  k_convert_all<<<2048, 256, 0, stream>>>(q, k, v, qb, kb, vb, Vsm);
  k_transpose_all<<<1152, 256, 0, stream>>>(w_qs, w_ks, w_vs, fc_w, resid_w,
                                            wqsT, wksT, wvsT, fcwT, rswT);
  k_gemm_bt<<<512, 256, 0, stream>>>(qb, wqsT, Qp, 1024, 768, 0.125f);
  k_gemm_bt<<<512, 256, 0, stream>>>(kb, wksT, Kp, 1024, 1024, 1.0f);
  k_gemm_bt<<<512, 256, 0, stream>>>(vb, wvsT, Vp, 1024, 1024, 1.0f);
  k_transpose_v<<<2048, 256, 0, stream>>>(Vp, VtT, Vsm);
  k_attn<<<2048, 256, 0, stream>>>(Qp, Kp, VtT, Vsm, Aout);
  k_gemm_final<<<512, 256, 0, stream>>>(Aout, fcwT, 1024, qb, rswT, 768, resid_b, Y, 1024);
  k_ln<<<8192, 256, 0, stream>>>(Y, ln_g, ln_b, out);
}